// Round 6
// baseline (17.291 us; speedup 1.0000x reference)
//
#include <hip/hip_runtime.h>

// PlaceCellNetwork — closed-form fixed point (round-2 derivation):
//   Y[n,j] = max( X[n,:].W[j,:] - b[j], 0 ) / (denom_j + dM_j)
// Memory-bound: 3 MB read + 21 MB write.
//
// History: r2 flat+LDS = 10.9us; r4 gridstride+nt = 15.9; r5 gridstride+plain
// = 13.4 -> flat mapping wins; nt stores lose. This round: flat mapping, NO
// LDS / NO barrier — per-thread direct loads of the tiny (L1-resident) W/M/b
// tables + v_rcp, eliminating the 5120 per-block prologue barriers.

#define PCN_N    262144
#define PCN_DIN  3
#define PCN_DOUT 20
#define BLOCK    256
#define TOTAL4   (PCN_N * (PCN_DOUT / 4))   // 1,310,720 float4 stores
#define GRID     (TOTAL4 / BLOCK)           // 5120, exact

typedef float fvec4 __attribute__((ext_vector_type(4)));

__global__ __launch_bounds__(BLOCK)
void pcn_flat_kernel(const float* __restrict__ X,
                     const float* __restrict__ W,
                     const float* __restrict__ M,
                     const float* __restrict__ b,
                     float* __restrict__ Yout) {
    int tid = blockIdx.x * BLOCK + threadIdx.x;   // exact fit, no guard
    int n   = tid / 5;                            // magic-mul
    int jb  = (tid - n * 5) * 4;                  // 0,4,8,12,16

    const float* Xr = X + n * PCN_DIN;
    float x0 = Xr[0];
    float x1 = Xr[1];
    float x2 = Xr[2];

    fvec4 o;
    #pragma unroll
    for (int k = 0; k < 4; ++k) {
        int j = jb + k;
        float dM  = M[j * (PCN_DOUT + 1)];               // diag(M)[j], L1-hot
        float inv = __builtin_amdgcn_rcpf(dM + dM);      // 1/(denom+dM), LBD2=0
        float d = fmaf(x0, W[j * PCN_DIN + 0],
                  fmaf(x1, W[j * PCN_DIN + 1],
                  fmaf(x2, W[j * PCN_DIN + 2], -b[j]))); // ALPHA=1
        o[k] = fmaxf(d, 0.0f) * inv;
    }

    reinterpret_cast<fvec4*>(Yout)[tid] = o;
}

extern "C" void kernel_launch(void* const* d_in, const int* in_sizes, int n_in,
                              void* d_out, int out_size, void* d_ws, size_t ws_size,
                              hipStream_t stream) {
    const float* X = (const float*)d_in[0];
    const float* W = (const float*)d_in[1];
    const float* M = (const float*)d_in[2];
    const float* b = (const float*)d_in[3];
    float* Yout = (float*)d_out;

    pcn_flat_kernel<<<GRID, BLOCK, 0, stream>>>(X, W, M, b, Yout);
}

// Round 7
// 11.314 us; speedup vs baseline: 1.5283x; 1.5283x over previous
//
#include <hip/hip_runtime.h>

// PlaceCellNetwork — closed-form fixed point (round-2 derivation):
//   Y[n,j] = max( X[n,:].W[j,:] - b[j], 0 ) / (denom_j + dM_j)
// Memory-bound: 3 MB read + 21 MB write.
//
// History: r2 flat+LDS+256thr = 10.9us (best); r4 nt-stores = 15.9;
// r5 grid-stride far writes = 13.4; r6 no-LDS per-thread coeff loads = 17.3.
// Lesson: dense in-order single-frontier float4 writes + LDS coeff broadcast
// win. This round: identical structure, 512-thread blocks (2560 blocks =
// half the prologues/barriers/dispatches), exact-fit grid, no tail guard.

#define PCN_N    262144
#define PCN_DIN  3
#define PCN_DOUT 20
#define BLOCK    512
#define TOTAL4   (PCN_N * (PCN_DOUT / 4))   // 1,310,720 float4 stores
#define GRID     (TOTAL4 / BLOCK)           // 2560, exact

typedef float fvec4 __attribute__((ext_vector_type(4)));

__global__ __launch_bounds__(BLOCK)
void pcn_flat_kernel(const float* __restrict__ X,
                     const float* __restrict__ W,
                     const float* __restrict__ M,
                     const float* __restrict__ b,
                     float* __restrict__ Yout) {
    constexpr float ALPHA = 1.0f, LBD2 = 0.0f;

    // c[j] = {w0,w1,w2,-alpha*b[j]} * 1/(denom+dM); pad row to 5 floats so
    // jb in {0,4,8,12,16} maps to banks {0,20,8,28,16}+k — conflict-free.
    __shared__ float c[PCN_DOUT][5];
    int t = threadIdx.x;
    if (t < PCN_DOUT) {
        float dM = M[t * PCN_DOUT + t];
        float inv = 1.0f / ((LBD2 + dM) + dM);
        c[t][0] = W[t * PCN_DIN + 0] * inv;
        c[t][1] = W[t * PCN_DIN + 1] * inv;
        c[t][2] = W[t * PCN_DIN + 2] * inv;
        c[t][3] = -ALPHA * b[t] * inv;
    }
    __syncthreads();

    int tid = blockIdx.x * BLOCK + t;   // exact fit: 0 .. TOTAL4-1
    int n   = tid / 5;                  // magic-mul
    int jb  = (tid - n * 5) * 4;        // 0,4,8,12,16

    const float* Xr = X + n * PCN_DIN;
    float x0 = Xr[0];
    float x1 = Xr[1];
    float x2 = Xr[2];

    fvec4 o;
    #pragma unroll
    for (int k = 0; k < 4; ++k) {
        const float* cj = c[jb + k];
        o[k] = fmaxf(fmaf(x0, cj[0], fmaf(x1, cj[1], fmaf(x2, cj[2], cj[3]))), 0.0f);
    }

    reinterpret_cast<fvec4*>(Yout)[tid] = o;   // dense, in-order write frontier
}

extern "C" void kernel_launch(void* const* d_in, const int* in_sizes, int n_in,
                              void* d_out, int out_size, void* d_ws, size_t ws_size,
                              hipStream_t stream) {
    const float* X = (const float*)d_in[0];
    const float* W = (const float*)d_in[1];
    const float* M = (const float*)d_in[2];
    const float* b = (const float*)d_in[3];
    float* Yout = (float*)d_out;

    pcn_flat_kernel<<<GRID, BLOCK, 0, stream>>>(X, W, M, b, Yout);
}

// Round 8
// 10.900 us; speedup vs baseline: 1.5864x; 1.0380x over previous
//
#include <hip/hip_runtime.h>

// PlaceCellNetwork — closed-form fixed point (round-2 derivation):
//   Y[n,j] = max( X[n,:].W[j,:] - b[j], 0 ) / (denom_j + dM_j)
// Memory-bound: 3 MB read + 21 MB write; floor ~= launch/ramp (~7us) +
// 24MB @ 6.7TB/s (3.6us).
//
// History: r2 flat+LDS+256thr = 10.9us (BEST); r4 nt-stores = 15.9;
// r5 grid-stride = 13.4; r6 no-LDS = 17.3; r7 512thr = 11.3.
// This round: lock in the r2 structure (256-thread blocks, one float4 per
// thread, LDS coefficient broadcast, dense in-order write frontier).

#define PCN_N    262144
#define PCN_DIN  3
#define PCN_DOUT 20
#define BLOCK    256
#define TOTAL4   (PCN_N * (PCN_DOUT / 4))   // 1,310,720 float4 stores
#define GRID     (TOTAL4 / BLOCK)           // 5120, exact

typedef float fvec4 __attribute__((ext_vector_type(4)));

__global__ __launch_bounds__(BLOCK)
void pcn_flat_kernel(const float* __restrict__ X,
                     const float* __restrict__ W,
                     const float* __restrict__ M,
                     const float* __restrict__ b,
                     float* __restrict__ Yout) {
    constexpr float ALPHA = 1.0f, LBD2 = 0.0f;

    // c[j] = {w0,w1,w2,-alpha*b[j]} * 1/(denom+dM); pad row to 5 floats so
    // jb in {0,4,8,12,16} maps to banks {0,20,8,28,16}+k — conflict-free.
    __shared__ float c[PCN_DOUT][5];
    int t = threadIdx.x;
    if (t < PCN_DOUT) {
        float dM = M[t * PCN_DOUT + t];
        float inv = 1.0f / ((LBD2 + dM) + dM);
        c[t][0] = W[t * PCN_DIN + 0] * inv;
        c[t][1] = W[t * PCN_DIN + 1] * inv;
        c[t][2] = W[t * PCN_DIN + 2] * inv;
        c[t][3] = -ALPHA * b[t] * inv;
    }
    __syncthreads();

    int tid = blockIdx.x * BLOCK + t;   // exact fit: 0 .. TOTAL4-1
    int n   = tid / 5;                  // magic-mul
    int jb  = (tid - n * 5) * 4;        // 0,4,8,12,16

    const float* Xr = X + n * PCN_DIN;
    float x0 = Xr[0];
    float x1 = Xr[1];
    float x2 = Xr[2];

    fvec4 o;
    #pragma unroll
    for (int k = 0; k < 4; ++k) {
        const float* cj = c[jb + k];
        o[k] = fmaxf(fmaf(x0, cj[0], fmaf(x1, cj[1], fmaf(x2, cj[2], cj[3]))), 0.0f);
    }

    reinterpret_cast<fvec4*>(Yout)[tid] = o;   // dense, in-order write frontier
}

extern "C" void kernel_launch(void* const* d_in, const int* in_sizes, int n_in,
                              void* d_out, int out_size, void* d_ws, size_t ws_size,
                              hipStream_t stream) {
    const float* X = (const float*)d_in[0];
    const float* W = (const float*)d_in[1];
    const float* M = (const float*)d_in[2];
    const float* b = (const float*)d_in[3];
    float* Yout = (float*)d_out;

    pcn_flat_kernel<<<GRID, BLOCK, 0, stream>>>(X, W, M, b, Yout);
}